// Round 1
// 1460.648 us; speedup vs baseline: 1.0709x; 1.0709x over previous
//
#include <hip/hip_runtime.h>
#include <math.h>

#define BATCH   4
#define SEQ     2048
#define DMODEL  768
#define DSTATE  16
#define DCONV   4
#define HEADDIM 64
#define DINNER  1536
#define NHEADS  24
#define CONVDIM 1568
#define DINPROJ 3128
#define DFFN    3072
#define ROWS    (BATCH*SEQ)   // 8192
#define QCH     128           // scan chunk length
#define NCHUNK  (SEQ/QCH)     // 16

typedef __attribute__((ext_vector_type(8))) short bhalf8;   // 8 bf16 (4 VGPRs)
typedef __attribute__((ext_vector_type(4))) float floatx4;  // 4 fp32 acc

__device__ __forceinline__ float gelu_f(float x) {
    return 0.5f * x * (1.0f + erff(x * 0.70710678118654752f));
}

// RNE split: v ~= hi + lo (bf16 each), both rounded-to-nearest-even
__device__ __forceinline__ void splitRNE(float v, unsigned short& h, unsigned short& l) {
    unsigned u = __float_as_uint(v);
    unsigned rr = u + 0x7FFFu + ((u >> 16) & 1u);
    unsigned short hi = (unsigned short)(rr >> 16);
    float rem = v - __uint_as_float(((unsigned)hi) << 16);
    unsigned u2 = __float_as_uint(rem);
    unsigned r2 = u2 + 0x7FFFu + ((u2 >> 16) & 1u);
    h = hi;
    l = (unsigned short)(r2 >> 16);
}

// async global->LDS DMA, 16B per lane (dest = wave-uniform base + lane*16)
__device__ __forceinline__ void gl16(const unsigned short* g, unsigned short* l) {
    __builtin_amdgcn_global_load_lds(
        (const __attribute__((address_space(1))) void*)g,
        (__attribute__((address_space(3))) void*)l, 16, 0, 0);
}

// ---------------- block reduction (256 threads, wave64) ----------------
__device__ __forceinline__ float2 blockReduce2(float a, float b) {
    #pragma unroll
    for (int o = 32; o > 0; o >>= 1) {
        a += __shfl_down(a, o, 64);
        b += __shfl_down(b, o, 64);
    }
    __shared__ float sa[4], sb[4];
    int w = threadIdx.x >> 6, lane = threadIdx.x & 63;
    if (lane == 0) { sa[w] = a; sb[w] = b; }
    __syncthreads();
    if (threadIdx.x == 0) {
        int nw = blockDim.x >> 6;
        for (int i = 1; i < nw; ++i) { a += sa[i]; b += sb[i]; }
        sa[0] = a; sb[0] = b;
    }
    __syncthreads();
    return make_float2(sa[0], sb[0]);
}

// ---------------- LayerNorm, fp32 out (final, with residual) -------------
__global__ __launch_bounds__(256) void ln_kernel(
    const float* __restrict__ x, const float* __restrict__ res,
    const float* __restrict__ w, const float* __restrict__ b,
    float* __restrict__ out)
{
    int r = blockIdx.x;
    const float* xr = x + (size_t)r * DMODEL;
    float v[3]; float s = 0.f, ss = 0.f;
    #pragma unroll
    for (int i = 0; i < 3; ++i) {
        int c = threadIdx.x + i * 256;
        float t = xr[c];
        if (res) t += res[(size_t)r * DMODEL + c];
        v[i] = t; s += t; ss += t * t;
    }
    float2 red = blockReduce2(s, ss);
    float mean = red.x * (1.0f / DMODEL);
    float var  = red.y * (1.0f / DMODEL) - mean * mean;
    float inv  = rsqrtf(var + 1e-5f);
    #pragma unroll
    for (int i = 0; i < 3; ++i) {
        int c = threadIdx.x + i * 256;
        out[(size_t)r * DMODEL + c] = (v[i] - mean) * inv * w[c] + b[c];
    }
}

// ---------------- LayerNorm, bf16 hi/lo plane out (xn for in_proj) -------
__global__ __launch_bounds__(256) void ln_split_kernel(
    const float* __restrict__ x,
    const float* __restrict__ w, const float* __restrict__ b,
    unsigned short* __restrict__ H, unsigned short* __restrict__ L)
{
    int r = blockIdx.x;
    const float* xr = x + (size_t)r * DMODEL;
    float v[3]; float s = 0.f, ss = 0.f;
    #pragma unroll
    for (int i = 0; i < 3; ++i) {
        int c = threadIdx.x + i * 256;
        float t = xr[c];
        v[i] = t; s += t; ss += t * t;
    }
    float2 red = blockReduce2(s, ss);
    float mean = red.x * (1.0f / DMODEL);
    float var  = red.y * (1.0f / DMODEL) - mean * mean;
    float inv  = rsqrtf(var + 1e-5f);
    #pragma unroll
    for (int i = 0; i < 3; ++i) {
        int c = threadIdx.x + i * 256;
        float o = (v[i] - mean) * inv * w[c] + b[c];
        unsigned short h, l;
        splitRNE(o, h, l);
        H[(size_t)r * DMODEL + c] = h;
        L[(size_t)r * DMODEL + c] = l;
    }
}

// ---------------- weight transpose + bf16 hi/lo split ---------------------
// in : W[K][N] fp32 ; out: TH[N][K], TL[N][K] bf16 (RNE hi, RNE lo)
__global__ __launch_bounds__(256) void wconv(
    const float* __restrict__ W, unsigned short* __restrict__ TH,
    unsigned short* __restrict__ TL, int K, int N)
{
    __shared__ float t[32][33];
    int tx = threadIdx.x & 31, ty = threadIdx.x >> 5;  // ty 0..7
    int kb = blockIdx.y * 32, nb = blockIdx.x * 32;
    #pragma unroll
    for (int i = 0; i < 4; ++i) {
        int k = kb + ty + i * 8, n = nb + tx;
        t[ty + i * 8][tx] = (k < K && n < N) ? W[(size_t)k * N + n] : 0.f;
    }
    __syncthreads();
    #pragma unroll
    for (int i = 0; i < 4; ++i) {
        int n = nb + ty + i * 8, k = kb + tx;
        if (n < N && k < K) {
            unsigned short hi, lo;
            splitRNE(t[tx][ty + i * 8], hi, lo);
            TH[(size_t)n * K + k] = hi;
            TL[(size_t)n * K + k] = lo;
        }
    }
}

// ---------------- bf16x3 split-GEMM via MFMA ------------------------------
// A: pre-split bf16 planes AH/AL [M][K]; B: weight planes BH/BL [N][K].
// C out either fp32 (C) or bf16 hi/lo planes (CHo/CLo).
// Staging: global_load_lds 16B DMA into linear LDS with XOR slot swizzle
// (slot ^= (row>>1)&3) pre-applied on the global source address; frag reads
// apply the same XOR -> 64-lane ds_read_b128 hits all 8 4-bank groups
// evenly (2 lanes/bank = conflict-free).
__global__ __launch_bounds__(256) void gemm3(
    const unsigned short* __restrict__ AHg, const unsigned short* __restrict__ ALg,
    const unsigned short* __restrict__ BHg, const unsigned short* __restrict__ BLg,
    float* __restrict__ C, unsigned short* __restrict__ CHo, unsigned short* __restrict__ CLo,
    const float* __restrict__ bias,
    int M, int N, int K, int ldc, int coloff,
    int revA, int revC, int act)
{
    (void)M;
    __shared__ __align__(16) unsigned short AsH[128 * 32], AsL[128 * 32];
    __shared__ __align__(16) unsigned short BsH[128 * 32], BsL[128 * 32];

    const int tid = threadIdx.x;
    const int m0 = blockIdx.y * 128;
    const int n0 = blockIdx.x * 128;

    // staging: each thread owns two 16B chunks per buffer
    size_t aoff[2], boff[2];
    int lofs[2];
    #pragma unroll
    for (int q = 0; q < 2; ++q) {
        int row = (tid >> 2) + 64 * q;
        int sd  = (tid & 3) ^ ((row >> 1) & 3);   // inverse-swizzled data slot
        int ar = m0 + row;
        if (revA) ar = (ar & ~(SEQ - 1)) + (SEQ - 1 - (ar & (SEQ - 1)));
        aoff[q] = (size_t)ar * K + sd * 8;
        boff[q] = (size_t)(n0 + row) * K + sd * 8;
        lofs[q] = (tid + 256 * q) * 8;            // linear LDS dest (ushorts)
    }

    auto stage = [&](int k0) {
        #pragma unroll
        for (int q = 0; q < 2; ++q) {
            gl16(AHg + aoff[q] + k0, AsH + lofs[q]);
            gl16(ALg + aoff[q] + k0, AsL + lofs[q]);
            gl16(BHg + boff[q] + k0, BsH + lofs[q]);
            gl16(BLg + boff[q] + k0, BsL + lofs[q]);
        }
    };

    auto frag = [&](const unsigned short* buf, int row, int slot) -> bhalf8 {
        int sp = slot ^ ((row >> 1) & 3);
        return *(const bhalf8*)(buf + row * 32 + sp * 8);
    };

    // wave layout: 2x2, each wave owns a 64x64 quadrant
    const int w = tid >> 6, lane = tid & 63;
    const int rw = (w >> 1) * 64, cw = (w & 1) * 64;
    const int lr = lane & 15;   // m/n within 16-tile
    const int lq = lane >> 4;   // quad -> k slot (frags), row group (C)

    floatx4 acc[4][4];
    const floatx4 fz = {0.f, 0.f, 0.f, 0.f};
    #pragma unroll
    for (int i = 0; i < 4; ++i)
        #pragma unroll
        for (int j = 0; j < 4; ++j) acc[i][j] = fz;

    const int ktiles = K >> 5;   // K % 32 == 0 for all our GEMMs
    stage(0);
    for (int kt = 0; kt < ktiles; ++kt) {
        __syncthreads();                     // drains vmcnt(0): tile visible
        bhalf8 ah[4], al[4], bh[4], bl[4];
        #pragma unroll
        for (int i = 0; i < 4; ++i) {
            int ra = rw + i * 16 + lr;
            int rb = cw + i * 16 + lr;
            ah[i] = frag(AsH, ra, lq);
            al[i] = frag(AsL, ra, lq);
            bh[i] = frag(BsH, rb, lq);
            bl[i] = frag(BsL, rb, lq);
        }
        __syncthreads();                     // all lanes' ds_reads retired
        if (kt + 1 < ktiles) stage((kt + 1) * 32);  // DMA overlaps MFMAs below
        #pragma unroll
        for (int i = 0; i < 4; ++i)
            #pragma unroll
            for (int j = 0; j < 4; ++j) {
                acc[i][j] = __builtin_amdgcn_mfma_f32_16x16x32_bf16(ah[i], bh[j], acc[i][j], 0, 0, 0);
                acc[i][j] = __builtin_amdgcn_mfma_f32_16x16x32_bf16(ah[i], bl[j], acc[i][j], 0, 0, 0);
                acc[i][j] = __builtin_amdgcn_mfma_f32_16x16x32_bf16(al[i], bh[j], acc[i][j], 0, 0, 0);
            }
    }

    // epilogue: C/D layout col=lane&15, row=quad*4+reg
    #pragma unroll
    for (int i = 0; i < 4; ++i) {
        #pragma unroll
        for (int j = 0; j < 4; ++j) {
            int gc = n0 + cw + j * 16 + lr;
            if (gc < N) {
                float bv = bias ? bias[gc] : 0.f;
                #pragma unroll
                for (int rg = 0; rg < 4; ++rg) {
                    int gm = m0 + rw + i * 16 + lq * 4 + rg;
                    if (revC) gm = (gm & ~(SEQ - 1)) + (SEQ - 1 - (gm & (SEQ - 1)));
                    float v = acc[i][j][rg] + bv;
                    if (act) v = gelu_f(v);
                    size_t o = (size_t)gm * ldc + coloff + gc;
                    if (CHo) {
                        unsigned short h, l;
                        splitRNE(v, h, l);
                        CHo[o] = h; CLo[o] = l;
                    } else {
                        C[o] = v;
                    }
                }
            }
        }
    }
}

// ---------------- depthwise causal conv + SiLU ----------------
__global__ __launch_bounds__(256) void conv_kernel(
    const float* __restrict__ zx, const float* __restrict__ cw,
    const float* __restrict__ cb, float* __restrict__ xcv,
    float* __restrict__ bc)
{
    int c = blockIdx.x * 256 + threadIdx.x;
    int r = blockIdx.y;
    if (c >= CONVDIM) return;
    int t = r & (SEQ - 1);
    int rb = r & ~(SEQ - 1);
    float acc = cb[c];
    #pragma unroll
    for (int k = 0; k < DCONV; ++k) {
        int tt = t - (DCONV - 1) + k;
        if (tt >= 0)
            acc += cw[c * DCONV + k] * zx[(size_t)(rb + tt) * DINPROJ + DINNER + c];
    }
    float v = acc / (1.0f + expf(-acc));   // silu
    if (c < DINNER) xcv[(size_t)r * DINNER + c] = v;
    else            bc[(size_t)r * 32 + (c - DINNER)] = v;
}

// ---------------- dt = softplus(z + bias), dA = exp(dt * -exp(A_log)) -----
__global__ __launch_bounds__(256) void dt_kernel(
    const float* __restrict__ zx, const float* __restrict__ dt_bias,
    const float* __restrict__ A_log, float* __restrict__ dtda)
{
    int i = blockIdx.x * 256 + threadIdx.x;
    if (i >= ROWS * NHEADS) return;
    int r = i / NHEADS, h = i - r * NHEADS;
    float v = zx[(size_t)r * DINPROJ + (DINPROJ - NHEADS) + h] + dt_bias[h];
    float dt = (v > 20.f) ? v : log1pf(expf(v));
    float A = -expf(A_log[h]);
    dtda[(size_t)r * 48 + h] = dt;
    dtda[(size_t)r * 48 + 24 + h] = expf(dt * A);
}

// ---------------- chunked scan, phase A: per-chunk local scan -------------
__global__ __launch_bounds__(64) void scan_a(
    const float* __restrict__ xcv, const float* __restrict__ bc,
    const float* __restrict__ dtda, const float* __restrict__ Dp,
    float* __restrict__ yout, float* __restrict__ S, float* __restrict__ cd)
{
    int blk = blockIdx.x;
    int bh = blk / NCHUNK, c = blk - bh * NCHUNK;
    int b = bh / NHEADS, h = bh - b * NHEADS;
    int p = threadIdx.x;
    float hs[DSTATE] = {};
    float Dv = Dp[h];
    float cum = 1.f;
    int t0 = c * QCH;
    for (int t = t0; t < t0 + QCH; ++t) {
        size_t r = (size_t)b * SEQ + t;
        float dt = dtda[r * 48 + h];
        float dA = dtda[r * 48 + 24 + h];
        float x  = xcv[r * DINNER + h * HEADDIM + p];
        cum *= dA;
        float coef = dt * x;
        const float* bcr = bc + r * 32;
        float y = 0.f;
        #pragma unroll
        for (int n = 0; n < DSTATE; ++n) {
            hs[n] = hs[n] * dA + coef * bcr[n];
            y += hs[n] * bcr[16 + n];
        }
        yout[r * DINPROJ + DINNER + h * HEADDIM + p] = y + Dv * x;
        if (p == 0) cd[r * NHEADS + h] = cum;
    }
    float* Sp = S + (((size_t)bh * NCHUNK + c) * HEADDIM + p) * DSTATE;
    #pragma unroll
    for (int n = 0; n < DSTATE; ++n) Sp[n] = hs[n];
}

// ---------------- chunked scan, phase B: sequential chunk combine ---------
__global__ __launch_bounds__(64) void scan_b(
    const float* __restrict__ cd, float* __restrict__ S)
{
    int bh = blockIdx.x;
    int b = bh / NHEADS, h = bh - b * NHEADS;
    int p = threadIdx.x;
    float H[DSTATE] = {};
    for (int c = 0; c < NCHUNK; ++c) {
        float* Sp = S + (((size_t)bh * NCHUNK + c) * HEADDIM + p) * DSTATE;
        float P = cd[((size_t)b * SEQ + c * QCH + QCH - 1) * NHEADS + h];
        float s[DSTATE];
        #pragma unroll
        for (int n = 0; n < DSTATE; ++n) s[n] = Sp[n];
        #pragma unroll
        for (int n = 0; n < DSTATE; ++n) Sp[n] = H[n];
        #pragma unroll
        for (int n = 0; n < DSTATE; ++n) H[n] = P * H[n] + s[n];
    }
}

// ---------------- chunked scan, phase C: carry correction -----------------
__global__ __launch_bounds__(64) void scan_c(
    const float* __restrict__ bc, const float* __restrict__ cd,
    const float* __restrict__ S, float* __restrict__ yout)
{
    int blk = blockIdx.x;
    int bh = blk / (NCHUNK - 1), c = blk - bh * (NCHUNK - 1) + 1;
    int b = bh / NHEADS, h = bh - b * NHEADS;
    int p = threadIdx.x;
    const float* Hp = S + (((size_t)bh * NCHUNK + c) * HEADDIM + p) * DSTATE;
    float H[DSTATE];
    #pragma unroll
    for (int n = 0; n < DSTATE; ++n) H[n] = Hp[n];
    int t0 = c * QCH;
    for (int t = t0; t < t0 + QCH; ++t) {
        size_t r = (size_t)b * SEQ + t;
        const float* Cr = bc + r * 32 + 16;
        float dot = 0.f;
        #pragma unroll
        for (int n = 0; n < DSTATE; ++n) dot += H[n] * Cr[n];
        float cum = cd[r * NHEADS + h];
        yout[r * DINPROJ + DINNER + h * HEADDIM + p] += cum * dot;
    }
}

// ---------------- gated RMSNorm -> bf16 hi/lo planes ----------------------
__global__ __launch_bounds__(256) void gnorm_kernel(
    const float* __restrict__ zx, const float* __restrict__ nw,
    unsigned short* __restrict__ H, unsigned short* __restrict__ L)
{
    int r = blockIdx.x;
    const float* zr = zx + (size_t)r * DINPROJ;
    float v[6]; float ss = 0.f;
    #pragma unroll
    for (int i = 0; i < 6; ++i) {
        int c = threadIdx.x + i * 256;
        float z = zr[c];
        float y = zr[DINNER + c];
        float t = y * z / (1.0f + expf(-z));
        v[i] = t; ss += t * t;
    }
    float2 red = blockReduce2(ss, 0.f);
    float sc = rsqrtf(red.x * (1.0f / DINNER) + 1e-5f);
    #pragma unroll
    for (int i = 0; i < 6; ++i) {
        int c = threadIdx.x + i * 256;
        float o = v[i] * sc * nw[c];
        unsigned short h, l;
        splitRNE(o, h, l);
        H[(size_t)r * DINNER + c] = h;
        L[(size_t)r * DINNER + c] = l;
    }
}

extern "C" void kernel_launch(void* const* d_in, const int* in_sizes, int n_in,
                              void* d_out, int out_size, void* d_ws, size_t ws_size,
                              hipStream_t stream)
{
    (void)in_sizes; (void)n_in; (void)out_size; (void)ws_size;
    const float* x     = (const float*)d_in[0];
    const float* ln1w  = (const float*)d_in[1];
    const float* ln1b  = (const float*)d_in[2];
    const float* ln2w  = (const float*)d_in[3];
    const float* ln2b  = (const float*)d_in[4];
    const float* ffnw1 = (const float*)d_in[5];
    const float* ffnb1 = (const float*)d_in[6];
    const float* ffnw2 = (const float*)d_in[7];
    const float* ffnb2 = (const float*)d_in[8];
    // per direction: in_w, conv_w, conv_b, dt_bias, A_log, D, norm_w, out_w
    const float* p[2][8];
    for (int d = 0; d < 2; ++d)
        for (int i = 0; i < 8; ++i)
            p[d][i] = (const float*)d_in[9 + d * 8 + i];

    // Workspace (215.5 MB — same layout/footprint as the passing run):
    //   zx   : 8192*3128 fp32 (102.5 MB) — in_proj out (fp32; conv/dt/scan/
    //          gnorm read it); after dir loop, hmid bf16 planes alias here
    //          (2 x 8192*3072 ushort = 100.6 MB).
    //   bi   : 8192*1536 fp32 slot (50.3 MB) — now biH/biL bf16 planes.
    //   S    : 8192*1536 fp32 slot (50.3 MB) — xcv (fp32) -> zn planes ->
    //          ffn weight planes + ffo.
    //   Wbuf : 2402304 floats (9.6 MB) — direction weight hi/lo planes;
    //          aliases Sbuf+cdbf during the scan window (in_proj weights
    //          dead after the in_proj GEMM).
    //   bcb / dtda : small
    float* ws   = (float*)d_ws;
    float* zx   = ws;
    float* bi   = zx + (size_t)ROWS * DINPROJ;
    float* S    = bi + (size_t)ROWS * DINNER;
    float* Wbuf = S  + (size_t)ROWS * DINNER;
    float* bcb  = Wbuf + 2402304;
    float* dtda = bcb + (size_t)ROWS * 32;
    float* Sbuf = Wbuf;                       // alias (dead in_proj weights)
    float* cdbf = Wbuf + (size_t)BATCH * NHEADS * NCHUNK * HEADDIM * DSTATE;

    unsigned short* xnH = (unsigned short*)d_out;              // xn planes in d_out
    unsigned short* xnL = xnH + (size_t)ROWS * DMODEL;         // (exactly out_size)
    float* xcv = S;
    unsigned short* znH = (unsigned short*)S;                  // zn planes (xcv dead)
    unsigned short* znL = znH + (size_t)ROWS * DINNER;
    unsigned short* biH = (unsigned short*)bi;
    unsigned short* biL = biH + (size_t)ROWS * DINNER;
    unsigned short* hmH = (unsigned short*)zx;                 // hmid planes (zx dead)
    unsigned short* hmL = hmH + (size_t)ROWS * DFFN;
    float* ffo = S + 4718592;   // after ffn weight-plane region (18.9 MB)

    // 1. ln1: x -> xn bf16 hi/lo planes (in d_out)
    ln_split_kernel<<<ROWS, 256, 0, stream>>>(x, ln1w, ln1b, xnH, xnL);

    for (int d = 0; d < 2; ++d) {
        unsigned short* WH = (unsigned short*)Wbuf;
        // in_proj weights: [768][3128] -> T [3128][768] hi/lo planes
        unsigned short* WL = WH + (size_t)DINPROJ * DMODEL;
        wconv<<<dim3((DINPROJ + 31) / 32, DMODEL / 32), 256, 0, stream>>>(
            p[d][0], WH, WL, DMODEL, DINPROJ);
        // 2. in_proj: zx = xn(flip if d==1) @ in_w   [8192 x 3128] fp32 out
        gemm3<<<dim3((DINPROJ + 127) / 128, ROWS / 128), 256, 0, stream>>>(
            xnH, xnL, WH, WL, zx, nullptr, nullptr, nullptr,
            ROWS, DINPROJ, DMODEL, DINPROJ, 0, d, 0, 0);
        // 3. conv + silu -> xcv (head channels), bcb (B,C)
        conv_kernel<<<dim3(7, ROWS), 256, 0, stream>>>(zx, p[d][1], p[d][2], xcv, bcb);
        // 4. dt/dA
        dt_kernel<<<(ROWS * NHEADS + 255) / 256, 256, 0, stream>>>(
            zx, p[d][3], p[d][4], dtda);
        // 5. chunked scan -> y (+D*x) into zx cols [1536,3072)
        scan_a<<<BATCH * NHEADS * NCHUNK, 64, 0, stream>>>(
            xcv, bcb, dtda, p[d][5], zx, Sbuf, cdbf);
        scan_b<<<BATCH * NHEADS, 64, 0, stream>>>(cdbf, Sbuf);
        scan_c<<<BATCH * NHEADS * (NCHUNK - 1), 64, 0, stream>>>(
            bcb, cdbf, Sbuf, zx);
        // 6. gated RMSNorm -> zn bf16 planes (xcv dead)
        gnorm_kernel<<<ROWS, 256, 0, stream>>>(zx, p[d][6], znH, znL);
        // 7. out_proj: bi planes[:, d*768:(d+1)*768] = zn @ out_w, flip if d==1
        unsigned short* WL2 = WH + (size_t)DMODEL * DINNER;
        wconv<<<dim3(DMODEL / 32, DINNER / 32), 256, 0, stream>>>(
            p[d][7], WH, WL2, DINNER, DMODEL);
        gemm3<<<dim3(DMODEL / 128, ROWS / 128), 256, 0, stream>>>(
            znH, znL, WH, WL2, nullptr, biH, biL, nullptr,
            ROWS, DMODEL, DINNER, DINNER, d * DMODEL, 0, d, 0);
    }

    // 8. ffn1: hmid planes = split(gelu(bi @ w1 + b1))  [8192 x 3072]
    {
        unsigned short* WH = (unsigned short*)S;
        unsigned short* WL = WH + (size_t)DFFN * DINNER;
        wconv<<<dim3(DFFN / 32, DINNER / 32), 256, 0, stream>>>(
            ffnw1, WH, WL, DINNER, DFFN);
        gemm3<<<dim3(DFFN / 128, ROWS / 128), 256, 0, stream>>>(
            biH, biL, WH, WL, nullptr, hmH, hmL, ffnb1,
            ROWS, DFFN, DINNER, DFFN, 0, 0, 0, 1);
    }
    // 9. ffn2: ffo = gelu(hmid @ w2 + b2) [8192 x 768] fp32
    {
        unsigned short* WH = (unsigned short*)S;
        unsigned short* WL = WH + (size_t)DMODEL * DFFN;
        wconv<<<dim3(DMODEL / 32, DFFN / 32), 256, 0, stream>>>(
            ffnw2, WH, WL, DFFN, DMODEL);
        gemm3<<<dim3(DMODEL / 128, ROWS / 128), 256, 0, stream>>>(
            hmH, hmL, WH, WL, ffo, nullptr, nullptr, ffnb2,
            ROWS, DMODEL, DFFN, DMODEL, 0, 0, 0, 1);
    }
    // 10. final layernorm(x + ffo) -> out (xn planes dead)
    ln_kernel<<<ROWS, 256, 0, stream>>>(x, ffo, ln2w, ln2b, (float*)d_out);
}